// Round 3
// baseline (26.392 us; speedup 1.0000x reference)
//
#include <hip/hip_runtime.h>

// GMM 2D activation, fully learnable.
// x:(B,S,D) f32, means:(K,2), inv_var_covar:(K,2,2), weights:(1,1,D/2,K,2)
// out[b,s,2d+c] = x[b,s,2d+c] * sum_k exp(-0.5*diff^T Sinv_k diff) * w[d,k,c]
// B=4, S=2048, D=2048, K=4.
//
// Each thread owns ONE fixed float4-column (2 GMM pairs): weights hoisted,
// row loop is a pure x-stream. -0.5*log2e folded into icov -> exp2 direct.
// Non-temporal stores keep `out` from polluting L2/L3 (x stays resident).

#define ROW4    512           // float4s per row (D/4)
#define KCOMP   4
#define RPB     8             // rows per block
#define NROWS   8192          // B*S

typedef float f32x4 __attribute__((ext_vector_type(4)));

__global__ __launch_bounds__(256) void gmm2d_kernel(
    const f32x4* __restrict__ x4,
    const float* __restrict__ means,   // (K,2)
    const float* __restrict__ icov,    // (K,2,2)
    const f32x4* __restrict__ w4,      // [d][k][c] as float4s
    f32x4*       __restrict__ out4)
{
    // -0.5*log2(e): fold into icov so pdf = exp2(qscaled)  (v_exp_f32 direct)
    const float SC = -0.72134752044448170f;
    // Wave-uniform scalar loads -> SGPRs.
    float m0[KCOMP], m1[KCOMP], ia[KCOMP], ib[KCOMP], ic[KCOMP], idd[KCOMP];
#pragma unroll
    for (int k = 0; k < KCOMP; ++k) {
        m0[k]  = means[k * 2 + 0];
        m1[k]  = means[k * 2 + 1];
        ia[k]  = icov[k * 4 + 0] * SC;
        ib[k]  = icov[k * 4 + 1] * SC;
        ic[k]  = icov[k * 4 + 2] * SC;
        idd[k] = icov[k * 4 + 3] * SC;
    }

    // Fixed column for this thread: 2 colchunks of 256 float4 per row.
    const int colchunk = blockIdx.x & 1;
    const int rowgrp   = blockIdx.x >> 1;
    const int col4     = colchunk * 256 + threadIdx.x;   // [0, 512)
    const int dp       = col4 * 2;                       // pair index in row

    // Hoisted weights for pairs dp, dp+1 (cache-resident, loaded once).
    const f32x4 wa = w4[dp * 2 + 0];  // pair0: k0c0 k0c1 k1c0 k1c1
    const f32x4 wb = w4[dp * 2 + 1];  // pair0: k2c0 k2c1 k3c0 k3c1
    const f32x4 wc = w4[dp * 2 + 2];  // pair1
    const f32x4 wd = w4[dp * 2 + 3];  // pair1

    const long base = (long)(rowgrp * RPB) * ROW4 + col4;

    f32x4 xv[RPB];
#pragma unroll
    for (int r = 0; r < RPB; ++r)
        xv[r] = x4[base + (long)r * ROW4];

#pragma unroll
    for (int r = 0; r < RPB; ++r) {
        float p0[KCOMP], p1[KCOMP];
#pragma unroll
        for (int k = 0; k < KCOMP; ++k) {
            float d0 = xv[r].x - m0[k];
            float d1 = xv[r].y - m1[k];
            float q  = d0 * (ia[k] * d0 + ib[k] * d1) + d1 * (ic[k] * d0 + idd[k] * d1);
            p0[k] = __builtin_amdgcn_exp2f(q);
            float e0 = xv[r].z - m0[k];
            float e1 = xv[r].w - m1[k];
            float s  = e0 * (ia[k] * e0 + ib[k] * e1) + e1 * (ic[k] * e0 + idd[k] * e1);
            p1[k] = __builtin_amdgcn_exp2f(s);
        }
        float r00 = p0[0] * wa.x + p0[1] * wa.z + p0[2] * wb.x + p0[3] * wb.z;
        float r01 = p0[0] * wa.y + p0[1] * wa.w + p0[2] * wb.y + p0[3] * wb.w;
        float r10 = p1[0] * wc.x + p1[1] * wc.z + p1[2] * wd.x + p1[3] * wd.z;
        float r11 = p1[0] * wc.y + p1[1] * wc.w + p1[2] * wd.y + p1[3] * wd.w;

        f32x4 ov;
        ov.x = xv[r].x * r00;
        ov.y = xv[r].y * r01;
        ov.z = xv[r].z * r10;
        ov.w = xv[r].w * r11;
        __builtin_nontemporal_store(ov, &out4[base + (long)r * ROW4]);
    }
}

extern "C" void kernel_launch(void* const* d_in, const int* in_sizes, int n_in,
                              void* d_out, int out_size, void* d_ws, size_t ws_size,
                              hipStream_t stream) {
    const f32x4* x4    = (const f32x4*)d_in[0];
    const float* means = (const float*)d_in[1];
    const float* icov  = (const float*)d_in[2];
    const f32x4* w4    = (const f32x4*)d_in[3];
    f32x4*       out4  = (f32x4*)d_out;

    // 2 colchunks * (8192/8) rowgroups = 2048 blocks
    const int grid = 2 * (NROWS / RPB);
    gmm2d_kernel<<<grid, 256, 0, stream>>>(x4, means, icov, w4, out4);
}